// Round 5
// baseline (301.960 us; speedup 1.0000x reference)
//
#include <hip/hip_runtime.h>

#define FDIM 128
#define NBMAX 512   // coarse buckets (dst>>8); supports n <= 131072 (and n < 2^24 for packing)
#define EPB 4096    // edges per block in hist/scatter phases

__device__ __forceinline__ unsigned short f2bf(float f) {
    unsigned int u = __float_as_uint(f);
    unsigned int r = u + 0x7fffu + ((u >> 16) & 1u);  // RNE
    return (unsigned short)(r >> 16);
}

// ---------------- coarse histogram: bcnt[dst>>8] ----------------
__global__ __launch_bounds__(256) void k_bhist(const int* __restrict__ dst,
                                               int* __restrict__ bcnt, int e) {
    __shared__ int h[NBMAX];
    for (int i = threadIdx.x; i < NBMAX; i += 256) h[i] = 0;
    __syncthreads();
    int base = blockIdx.x * EPB;
    int end = min(base + EPB, e);
    for (int i = base + threadIdx.x; i < end; i += 256) atomicAdd(&h[dst[i] >> 8], 1);
    __syncthreads();
    for (int i = threadIdx.x; i < NBMAX; i += 256) {
        int c = h[i];
        if (c) atomicAdd(&bcnt[i], c);
    }
}

// ---------------- bucket scan: bbase (exclusive) + gcur init ----------------
__global__ __launch_bounds__(512) void k_bscan(const int* __restrict__ bcnt,
                                               int* __restrict__ bbase,
                                               int* __restrict__ gcur, int nb, int e) {
    __shared__ int sh[512];
    int v = (threadIdx.x < nb) ? bcnt[threadIdx.x] : 0;
    sh[threadIdx.x] = v;
    __syncthreads();
    for (int off = 1; off < 512; off <<= 1) {
        int t = (threadIdx.x >= off) ? sh[threadIdx.x - off] : 0;
        __syncthreads();
        sh[threadIdx.x] += t;
        __syncthreads();
    }
    int excl = sh[threadIdx.x] - v;
    if (threadIdx.x < nb) {
        bbase[threadIdx.x] = excl;
        gcur[threadIdx.x] = excl;
    }
    if (threadIdx.x == 0) bbase[nb] = e;
}

// ---------------- coarse scatter: coarse[p] = (src<<8)|(dst&255), bucketed ----------------
__global__ __launch_bounds__(256) void k_scatterA(const int* __restrict__ src,
                                                  const int* __restrict__ dst,
                                                  int* __restrict__ gcur,
                                                  unsigned int* __restrict__ coarse, int e) {
    __shared__ int cur[NBMAX];
    for (int i = threadIdx.x; i < NBMAX; i += 256) cur[i] = 0;
    __syncthreads();
    int base = blockIdx.x * EPB;
    int end = min(base + EPB, e);
    for (int i = base + threadIdx.x; i < end; i += 256) atomicAdd(&cur[dst[i] >> 8], 1);
    __syncthreads();
    for (int i = threadIdx.x; i < NBMAX; i += 256) {
        int c = cur[i];
        cur[i] = c ? atomicAdd(&gcur[i], c) : 0;
    }
    __syncthreads();
    for (int i = base + threadIdx.x; i < end; i += 256) {
        int d = dst[i];
        int p = atomicAdd(&cur[d >> 8], 1);
        coarse[p] = ((unsigned)src[i] << 8) | (unsigned)(d & 255);
    }
}

// ---------------- fused per-bucket finalize ----------------
// One block per 256-node bucket. Counts local degree (LDS), local scan gives
// row_start = bbase[b] + excl (ebuf is bucket-contiguous!), writes
// deg/dinv/row_start coalesced, then bins srcs into ebuf with LDS cursors.
__global__ __launch_bounds__(256) void k_bfin(const unsigned int* __restrict__ coarse,
                                              const int* __restrict__ bbase,
                                              int* __restrict__ deg, float* __restrict__ dinv,
                                              int* __restrict__ row_start,
                                              int* __restrict__ ebuf, int n) {
    __shared__ int ld[256];
    __shared__ int sc[256];
    __shared__ int cur[256];
    int b = blockIdx.x;
    int s = bbase[b], t = bbase[b + 1];
    ld[threadIdx.x] = 0;
    __syncthreads();
    for (int i = s + threadIdx.x; i < t; i += 256) atomicAdd(&ld[coarse[i] & 255u], 1);
    __syncthreads();
    int v = ld[threadIdx.x];  // deg-1 of this node
    sc[threadIdx.x] = v;
    __syncthreads();
    for (int off = 1; off < 256; off <<= 1) {
        int tv = (threadIdx.x >= off) ? sc[threadIdx.x - off] : 0;
        __syncthreads();
        sc[threadIdx.x] += tv;
        __syncthreads();
    }
    int rs = s + sc[threadIdx.x] - v;  // bucket base + exclusive scan
    cur[threadIdx.x] = rs;
    int node = b * 256 + threadIdx.x;
    if (node < n) {
        deg[node] = v + 1;
        dinv[node] = rsqrtf((float)(v + 1));
        row_start[node] = rs;
    }
    __syncthreads();
    for (int i = s + threadIdx.x; i < t; i += 256) {
        unsigned int p = coarse[i];
        int pos = atomicAdd(&cur[p & 255u], 1);
        ebuf[pos] = (int)(p >> 8);
    }
}

// ---------------- hs = bf16((x @ W) * dinv[row]) ----------------
// 512 threads; block computes 256 rows x 128 cols; thread micro-tile 8x8.
// W in LDS (64 KB -> 2 blocks/CU = 16 waves/CU).
__global__ __launch_bounds__(512) void k_gemm(
    const float* __restrict__ x, const float* __restrict__ W,
    const float* __restrict__ dinv, unsigned short* __restrict__ hs, int n) {
    __shared__ float Ws[FDIM * FDIM];  // 64 KB, row-major [k][c]
    {
        const float4* W4 = (const float4*)W;
        float4* Wl = (float4*)Ws;
        for (int i = threadIdx.x; i < FDIM * FDIM / 4; i += 512) Wl[i] = W4[i];
    }
    __syncthreads();

    const int cg = threadIdx.x & 15;   // col group
    const int rg = threadIdx.x >> 4;   // row group (0..31)
    const int row0 = blockIdx.x * 256 + rg * 8;
    const float4* Ws4 = (const float4*)Ws;

    const float4* xp[8];
    #pragma unroll
    for (int r = 0; r < 8; ++r) {
        int rc = row0 + r;
        if (rc >= n) rc = n - 1;
        xp[r] = (const float4*)(x + (size_t)rc * FDIM);
    }

    float4 acc[8][2];
    #pragma unroll
    for (int r = 0; r < 8; ++r) {
        acc[r][0] = make_float4(0.f, 0.f, 0.f, 0.f);
        acc[r][1] = make_float4(0.f, 0.f, 0.f, 0.f);
    }

    #pragma unroll 2
    for (int k4 = 0; k4 < FDIM / 4; ++k4) {
        float4 xv[8];
        #pragma unroll
        for (int r = 0; r < 8; ++r) xv[r] = xp[r][k4];
        #pragma unroll
        for (int kk = 0; kk < 4; ++kk) {
            float4 w0 = Ws4[(k4 * 4 + kk) * 32 + cg];
            float4 w1 = Ws4[(k4 * 4 + kk) * 32 + 16 + cg];
            #pragma unroll
            for (int r = 0; r < 8; ++r) {
                float xs = (kk == 0) ? xv[r].x : (kk == 1) ? xv[r].y : (kk == 2) ? xv[r].z : xv[r].w;
                acc[r][0].x += xs * w0.x;
                acc[r][0].y += xs * w0.y;
                acc[r][0].z += xs * w0.z;
                acc[r][0].w += xs * w0.w;
                acc[r][1].x += xs * w1.x;
                acc[r][1].y += xs * w1.y;
                acc[r][1].z += xs * w1.z;
                acc[r][1].w += xs * w1.w;
            }
        }
    }

    #pragma unroll
    for (int r = 0; r < 8; ++r) {
        int row = row0 + r;
        if (row >= n) break;
        float s = dinv[row];
        ushort4 p0, p1;
        p0.x = f2bf(acc[r][0].x * s);
        p0.y = f2bf(acc[r][0].y * s);
        p0.z = f2bf(acc[r][0].z * s);
        p0.w = f2bf(acc[r][0].w * s);
        p1.x = f2bf(acc[r][1].x * s);
        p1.y = f2bf(acc[r][1].y * s);
        p1.z = f2bf(acc[r][1].z * s);
        p1.w = f2bf(acc[r][1].w * s);
        *(ushort4*)(hs + (size_t)row * FDIM + cg * 4) = p0;
        *(ushort4*)(hs + (size_t)row * FDIM + 64 + cg * 4) = p1;
    }
}

// ---------------- gather: out[i] = dinv[i]*(hs[i] + sum hs[src]) + b ----------------
__global__ __launch_bounds__(256) void k_gather(
    const unsigned short* __restrict__ hs, const int* __restrict__ ebuf,
    const int* __restrict__ row_start, const int* __restrict__ deg,
    const float* __restrict__ dinv, const float* __restrict__ bias,
    float* __restrict__ out, int n) {
    int i = blockIdx.x * 4 + (threadIdx.x >> 6);
    if (i >= n) return;
    int lane = threadIdx.x & 63;

    int beg = row_start[i];
    int cnt = deg[i] - 1;
    int end = beg + cnt;

    unsigned int u = ((const unsigned int*)(hs + (size_t)i * FDIM))[lane];
    float ax = __uint_as_float(u << 16);
    float ay = __uint_as_float(u & 0xffff0000u);

    int j = beg;
    for (; j + 3 < end; j += 4) {
        int s0 = ebuf[j], s1 = ebuf[j + 1], s2 = ebuf[j + 2], s3 = ebuf[j + 3];
        unsigned int u0 = ((const unsigned int*)(hs + (size_t)s0 * FDIM))[lane];
        unsigned int u1 = ((const unsigned int*)(hs + (size_t)s1 * FDIM))[lane];
        unsigned int u2 = ((const unsigned int*)(hs + (size_t)s2 * FDIM))[lane];
        unsigned int u3 = ((const unsigned int*)(hs + (size_t)s3 * FDIM))[lane];
        ax += __uint_as_float(u0 << 16) + __uint_as_float(u1 << 16)
            + __uint_as_float(u2 << 16) + __uint_as_float(u3 << 16);
        ay += __uint_as_float(u0 & 0xffff0000u) + __uint_as_float(u1 & 0xffff0000u)
            + __uint_as_float(u2 & 0xffff0000u) + __uint_as_float(u3 & 0xffff0000u);
    }
    for (; j < end; ++j) {
        int s0 = ebuf[j];
        unsigned int u0 = ((const unsigned int*)(hs + (size_t)s0 * FDIM))[lane];
        ax += __uint_as_float(u0 << 16);
        ay += __uint_as_float(u0 & 0xffff0000u);
    }

    float sc = dinv[i];
    float2 bb = ((const float2*)bias)[lane];
    float2 r = make_float2(ax * sc + bb.x, ay * sc + bb.y);
    ((float2*)(out + (size_t)i * FDIM))[lane] = r;
}

extern "C" void kernel_launch(void* const* d_in, const int* in_sizes, int n_in,
                              void* d_out, int out_size, void* d_ws, size_t ws_size,
                              hipStream_t stream) {
    const float* x  = (const float*)d_in[0];
    const int*   ei = (const int*)d_in[1];     // [2, E] int32
    const float* W  = (const float*)d_in[2];
    const float* b  = (const float*)d_in[3];

    const int n = in_sizes[0] / FDIM;
    const int e = in_sizes[1] / 2;
    const int* src = ei;
    const int* dst = ei + e;
    float* out = (float*)d_out;

    const int nb = (n + 255) >> 8;              // coarse buckets
    const int eblocks = (e + EPB - 1) / EPB;

    char* ws = (char*)d_ws;
    size_t off = 0;
    auto alloc = [&](size_t bytes) {
        char* p = ws + off;
        off += (bytes + 511) & ~(size_t)511;
        return p;
    };
    int*            deg       = (int*)alloc((size_t)n * 4);
    float*          dinv      = (float*)alloc((size_t)n * 4);
    int*            row_start = (int*)alloc((size_t)n * 4);
    int*            bcnt      = (int*)alloc((size_t)NBMAX * 4);
    int*            bbase     = (int*)alloc((size_t)(NBMAX + 1) * 4);
    int*            gcur      = (int*)alloc((size_t)NBMAX * 4);
    unsigned int*   coarse    = (unsigned int*)alloc((size_t)e * 4);
    int*            ebuf      = (int*)alloc((size_t)e * 4);
    unsigned short* hs        = (unsigned short*)alloc((size_t)n * FDIM * 2);

    hipMemsetAsync(bcnt, 0, (size_t)NBMAX * 4, stream);

    k_bhist<<<eblocks, 256, 0, stream>>>(dst, bcnt, e);
    k_bscan<<<1, 512, 0, stream>>>(bcnt, bbase, gcur, nb, e);
    k_scatterA<<<eblocks, 256, 0, stream>>>(src, dst, gcur, coarse, e);
    k_bfin<<<nb, 256, 0, stream>>>(coarse, bbase, deg, dinv, row_start, ebuf, n);

    k_gemm<<<(n + 255) / 256, 512, 0, stream>>>(x, W, dinv, hs, n);

    {
        int blocks = (n + 3) / 4;
        k_gather<<<blocks, 256, 0, stream>>>(hs, ebuf, row_start, deg, dinv, b, out, n);
    }
}

// Round 6
// 259.039 us; speedup vs baseline: 1.1657x; 1.1657x over previous
//
#include <hip/hip_runtime.h>

#define FDIM 128
#define NBMAX 512   // coarse buckets (dst>>8); supports n <= 131072
#define EPB 4096    // edges per block in hist/scatter phases

typedef __attribute__((ext_vector_type(8))) short bf16x8;
typedef __attribute__((ext_vector_type(4))) float f32x4;

__device__ __forceinline__ unsigned short f2bf(float f) {
    unsigned int u = __float_as_uint(f);
    unsigned int r = u + 0x7fffu + ((u >> 16) & 1u);  // RNE
    return (unsigned short)(r >> 16);
}

// ---------------- coarse histogram: bcnt[dst>>8] ----------------
__global__ __launch_bounds__(256) void k_bhist(const int* __restrict__ dst,
                                               int* __restrict__ bcnt, int e) {
    __shared__ int h[NBMAX];
    for (int i = threadIdx.x; i < NBMAX; i += 256) h[i] = 0;
    __syncthreads();
    int base = blockIdx.x * EPB;
    int end = min(base + EPB, e);
    for (int i = base + threadIdx.x; i < end; i += 256) atomicAdd(&h[dst[i] >> 8], 1);
    __syncthreads();
    for (int i = threadIdx.x; i < NBMAX; i += 256) {
        int c = h[i];
        if (c) atomicAdd(&bcnt[i], c);
    }
}

// ---------------- bucket scan: bbase (exclusive) + gcur init ----------------
__global__ __launch_bounds__(512) void k_bscan(const int* __restrict__ bcnt,
                                               int* __restrict__ bbase,
                                               int* __restrict__ gcur, int nb, int e) {
    __shared__ int sh[512];
    int v = (threadIdx.x < nb) ? bcnt[threadIdx.x] : 0;
    sh[threadIdx.x] = v;
    __syncthreads();
    for (int off = 1; off < 512; off <<= 1) {
        int t = (threadIdx.x >= off) ? sh[threadIdx.x - off] : 0;
        __syncthreads();
        sh[threadIdx.x] += t;
        __syncthreads();
    }
    int excl = sh[threadIdx.x] - v;
    if (threadIdx.x < nb) {
        bbase[threadIdx.x] = excl;
        gcur[threadIdx.x] = excl;
    }
    if (threadIdx.x == 0) bbase[nb] = e;
}

// ---------------- coarse scatter: coarse[p] = (src<<8)|(dst&255), bucketed ----------------
__global__ __launch_bounds__(256) void k_scatterA(const int* __restrict__ src,
                                                  const int* __restrict__ dst,
                                                  int* __restrict__ gcur,
                                                  unsigned int* __restrict__ coarse, int e) {
    __shared__ int cur[NBMAX];
    for (int i = threadIdx.x; i < NBMAX; i += 256) cur[i] = 0;
    __syncthreads();
    int base = blockIdx.x * EPB;
    int end = min(base + EPB, e);
    for (int i = base + threadIdx.x; i < end; i += 256) atomicAdd(&cur[dst[i] >> 8], 1);
    __syncthreads();
    for (int i = threadIdx.x; i < NBMAX; i += 256) {
        int c = cur[i];
        cur[i] = c ? atomicAdd(&gcur[i], c) : 0;
    }
    __syncthreads();
    for (int i = base + threadIdx.x; i < end; i += 256) {
        int d = dst[i];
        int p = atomicAdd(&cur[d >> 8], 1);
        coarse[p] = ((unsigned)src[i] << 8) | (unsigned)(d & 255);
    }
}

// ---------------- fused per-bucket finalize ----------------
__global__ __launch_bounds__(256) void k_bfin(const unsigned int* __restrict__ coarse,
                                              const int* __restrict__ bbase,
                                              int* __restrict__ deg, float* __restrict__ dinv,
                                              int* __restrict__ row_start,
                                              int* __restrict__ ebuf, int n) {
    __shared__ int ld[256];
    __shared__ int sc[256];
    __shared__ int cur[256];
    int b = blockIdx.x;
    int s = bbase[b], t = bbase[b + 1];
    ld[threadIdx.x] = 0;
    __syncthreads();
    for (int i = s + threadIdx.x; i < t; i += 256) atomicAdd(&ld[coarse[i] & 255u], 1);
    __syncthreads();
    int v = ld[threadIdx.x];  // deg-1 of this node
    sc[threadIdx.x] = v;
    __syncthreads();
    for (int off = 1; off < 256; off <<= 1) {
        int tv = (threadIdx.x >= off) ? sc[threadIdx.x - off] : 0;
        __syncthreads();
        sc[threadIdx.x] += tv;
        __syncthreads();
    }
    int rs = s + sc[threadIdx.x] - v;  // bucket base + exclusive scan
    cur[threadIdx.x] = rs;
    int node = b * 256 + threadIdx.x;
    if (node < n) {
        deg[node] = v + 1;
        dinv[node] = rsqrtf((float)(v + 1));
        row_start[node] = rs;
    }
    __syncthreads();
    for (int i = s + threadIdx.x; i < t; i += 256) {
        unsigned int p = coarse[i];
        int pos = atomicAdd(&cur[p & 255u], 1);
        ebuf[pos] = (int)(p >> 8);
    }
}

// ---------------- W -> bf16 hi/lo, transposed [n][k], linear ----------------
__global__ __launch_bounds__(256) void k_wconv(const float* __restrict__ W,
                                               unsigned short* __restrict__ whl) {
    int id = blockIdx.x * 256 + threadIdx.x;  // 0..16383
    int k = id >> 7, nn = id & 127;
    float w = W[id];  // W[k][nn]
    unsigned short hi = f2bf(w);
    float hif = __uint_as_float(((unsigned)hi) << 16);
    unsigned short lo = f2bf(w - hif);
    whl[nn * FDIM + k] = hi;                 // [0][n][k]
    whl[FDIM * FDIM + nn * FDIM + k] = lo;   // [1][n][k]
}

// ---------------- hs = bf16((x @ W) * dinv[row]) via split-bf16 MFMA ----------------
// 256 threads = 4 waves; wave computes 16 rows x 128 cols.
// B (W^T hi/lo) staged in exactly-64KB LDS with XOR swizzle on 16B granules.
__global__ __launch_bounds__(256) void k_gemm(
    const float* __restrict__ x, const unsigned short* __restrict__ whl,
    const float* __restrict__ dinv, unsigned short* __restrict__ hs, int n) {
    __shared__ unsigned short Bs[2 * FDIM * FDIM];  // 65536 B exactly
    {
        // stage with swizzle: granule (16B = 8 bf16) g within row n moves to g^(n&15)
        const float4* g4 = (const float4*)whl;
        float4* l4 = (float4*)Bs;
        for (int i = threadIdx.x; i < 4096; i += 256) {
            int sel_n = i >> 4;          // sel*128 + n
            int g = i & 15;
            l4[sel_n * 16 + (g ^ (sel_n & 15))] = g4[i];
        }
    }
    __syncthreads();

    const int lane = threadIdx.x & 63;
    const int wid = threadIdx.x >> 6;
    const int m = lane & 15;
    const int quad = lane >> 4;
    const int row0 = blockIdx.x * 64 + wid * 16;

    int rowA = row0 + m;
    if (rowA >= n) rowA = n - 1;
    const float* xr = x + (size_t)rowA * FDIM;

    f32x4 acc[8];
    #pragma unroll
    for (int ct = 0; ct < 8; ++ct) acc[ct] = (f32x4){0.f, 0.f, 0.f, 0.f};

    #pragma unroll
    for (int kc = 0; kc < 4; ++kc) {
        const int kb = kc * 32 + quad * 8;
        float4 xa = *(const float4*)(xr + kb);
        float4 xb = *(const float4*)(xr + kb + 4);
        float v[8] = {xa.x, xa.y, xa.z, xa.w, xb.x, xb.y, xb.z, xb.w};
        bf16x8 ahi, alo;
        #pragma unroll
        for (int j = 0; j < 8; ++j) {
            unsigned short h = f2bf(v[j]);
            ahi[j] = (short)h;
            alo[j] = (short)f2bf(v[j] - __uint_as_float(((unsigned)h) << 16));
        }
        const int g = kc * 4 + quad;  // 16B-granule index of kb
        #pragma unroll
        for (int ct = 0; ct < 8; ++ct) {
            int nidx = ct * 16 + m;
            const bf16x8 bhi = *(const bf16x8*)(Bs + (size_t)nidx * FDIM + (g ^ m) * 8);
            const bf16x8 blo = *(const bf16x8*)(Bs + (size_t)(FDIM + nidx) * FDIM + (g ^ m) * 8);
            acc[ct] = __builtin_amdgcn_mfma_f32_16x16x32_bf16(ahi, bhi, acc[ct], 0, 0, 0);
            acc[ct] = __builtin_amdgcn_mfma_f32_16x16x32_bf16(alo, bhi, acc[ct], 0, 0, 0);
            acc[ct] = __builtin_amdgcn_mfma_f32_16x16x32_bf16(ahi, blo, acc[ct], 0, 0, 0);
        }
    }

    // epilogue: D[row=quad*4+r][col=ct*16+m]
    #pragma unroll
    for (int r = 0; r < 4; ++r) {
        int row = row0 + quad * 4 + r;
        if (row >= n) continue;
        float s = dinv[row];
        unsigned short* hrow = hs + (size_t)row * FDIM;
        #pragma unroll
        for (int ct = 0; ct < 8; ++ct) hrow[ct * 16 + m] = f2bf(acc[ct][r] * s);
    }
}

// ---------------- gather: out[i] = dinv[i]*(hs[i] + sum hs[src]) + b ----------------
__global__ __launch_bounds__(256) void k_gather(
    const unsigned short* __restrict__ hs, const int* __restrict__ ebuf,
    const int* __restrict__ row_start, const int* __restrict__ deg,
    const float* __restrict__ dinv, const float* __restrict__ bias,
    float* __restrict__ out, int n) {
    int i = blockIdx.x * 4 + (threadIdx.x >> 6);
    if (i >= n) return;
    int lane = threadIdx.x & 63;

    int beg = row_start[i];
    int cnt = deg[i] - 1;
    int end = beg + cnt;

    unsigned int u = ((const unsigned int*)(hs + (size_t)i * FDIM))[lane];
    float ax = __uint_as_float(u << 16);
    float ay = __uint_as_float(u & 0xffff0000u);

    int j = beg;
    for (; j + 3 < end; j += 4) {
        int s0 = ebuf[j], s1 = ebuf[j + 1], s2 = ebuf[j + 2], s3 = ebuf[j + 3];
        unsigned int u0 = ((const unsigned int*)(hs + (size_t)s0 * FDIM))[lane];
        unsigned int u1 = ((const unsigned int*)(hs + (size_t)s1 * FDIM))[lane];
        unsigned int u2 = ((const unsigned int*)(hs + (size_t)s2 * FDIM))[lane];
        unsigned int u3 = ((const unsigned int*)(hs + (size_t)s3 * FDIM))[lane];
        ax += __uint_as_float(u0 << 16) + __uint_as_float(u1 << 16)
            + __uint_as_float(u2 << 16) + __uint_as_float(u3 << 16);
        ay += __uint_as_float(u0 & 0xffff0000u) + __uint_as_float(u1 & 0xffff0000u)
            + __uint_as_float(u2 & 0xffff0000u) + __uint_as_float(u3 & 0xffff0000u);
    }
    for (; j < end; ++j) {
        int s0 = ebuf[j];
        unsigned int u0 = ((const unsigned int*)(hs + (size_t)s0 * FDIM))[lane];
        ax += __uint_as_float(u0 << 16);
        ay += __uint_as_float(u0 & 0xffff0000u);
    }

    float sc = dinv[i];
    float2 bb = ((const float2*)bias)[lane];
    float2 r = make_float2(ax * sc + bb.x, ay * sc + bb.y);
    ((float2*)(out + (size_t)i * FDIM))[lane] = r;
}

extern "C" void kernel_launch(void* const* d_in, const int* in_sizes, int n_in,
                              void* d_out, int out_size, void* d_ws, size_t ws_size,
                              hipStream_t stream) {
    const float* x  = (const float*)d_in[0];
    const int*   ei = (const int*)d_in[1];     // [2, E] int32
    const float* W  = (const float*)d_in[2];
    const float* b  = (const float*)d_in[3];

    const int n = in_sizes[0] / FDIM;
    const int e = in_sizes[1] / 2;
    const int* src = ei;
    const int* dst = ei + e;
    float* out = (float*)d_out;

    const int nb = (n + 255) >> 8;              // coarse buckets
    const int eblocks = (e + EPB - 1) / EPB;

    char* ws = (char*)d_ws;
    size_t off = 0;
    auto alloc = [&](size_t bytes) {
        char* p = ws + off;
        off += (bytes + 511) & ~(size_t)511;
        return p;
    };
    int*            deg       = (int*)alloc((size_t)n * 4);
    float*          dinv      = (float*)alloc((size_t)n * 4);
    int*            row_start = (int*)alloc((size_t)n * 4);
    int*            bcnt      = (int*)alloc((size_t)NBMAX * 4);
    int*            bbase     = (int*)alloc((size_t)(NBMAX + 1) * 4);
    int*            gcur      = (int*)alloc((size_t)NBMAX * 4);
    unsigned short* whl       = (unsigned short*)alloc((size_t)2 * FDIM * FDIM * 2);
    unsigned int*   coarse    = (unsigned int*)alloc((size_t)e * 4);
    int*            ebuf      = (int*)alloc((size_t)e * 4);
    unsigned short* hs        = (unsigned short*)alloc((size_t)n * FDIM * 2);

    hipMemsetAsync(bcnt, 0, (size_t)NBMAX * 4, stream);

    k_wconv<<<64, 256, 0, stream>>>(W, whl);
    k_bhist<<<eblocks, 256, 0, stream>>>(dst, bcnt, e);
    k_bscan<<<1, 512, 0, stream>>>(bcnt, bbase, gcur, nb, e);
    k_scatterA<<<eblocks, 256, 0, stream>>>(src, dst, gcur, coarse, e);
    k_bfin<<<nb, 256, 0, stream>>>(coarse, bbase, deg, dinv, row_start, ebuf, n);

    k_gemm<<<(n + 63) / 64, 256, 0, stream>>>(x, whl, dinv, hs, n);

    {
        int blocks = (n + 3) / 4;
        k_gather<<<blocks, 256, 0, stream>>>(hs, ebuf, row_start, deg, dinv, b, out, n);
    }
}

// Round 7
// 246.825 us; speedup vs baseline: 1.2234x; 1.0495x over previous
//
#include <hip/hip_runtime.h>

#define FDIM 128
#define NBMAX 512   // coarse buckets (dst>>8); supports n <= 131072
#define EPB 4096    // edges per block in hist/scatter phases

typedef __attribute__((ext_vector_type(8))) short bf16x8;
typedef __attribute__((ext_vector_type(4))) float f32x4;

__device__ __forceinline__ unsigned short f2bf(float f) {
    unsigned int u = __float_as_uint(f);
    unsigned int r = u + 0x7fffu + ((u >> 16) & 1u);  // RNE
    return (unsigned short)(r >> 16);
}

// ---------------- D1: fused coarse histogram + W->bf16(hi) transpose ----------------
__global__ __launch_bounds__(256) void k_prep(const int* __restrict__ dst,
                                              int* __restrict__ bcnt,
                                              const float* __restrict__ W,
                                              unsigned short* __restrict__ whi,
                                              int e, int ebl) {
    __shared__ int h[NBMAX];
    if ((int)blockIdx.x < ebl) {
        for (int i = threadIdx.x; i < NBMAX; i += 256) h[i] = 0;
        __syncthreads();
        int base = blockIdx.x * EPB;
        int end = min(base + EPB, e);
        for (int i = base + threadIdx.x; i < end; i += 256) atomicAdd(&h[dst[i] >> 8], 1);
        __syncthreads();
        for (int i = threadIdx.x; i < NBMAX; i += 256) {
            int c = h[i];
            if (c) atomicAdd(&bcnt[i], c);
        }
    } else {
        int id = ((int)blockIdx.x - ebl) * 256 + threadIdx.x;  // 0..16383
        int k = id >> 7, nn = id & 127;
        whi[nn * FDIM + k] = f2bf(W[id]);  // W[k][nn] -> whi[nn][k]
    }
}

// ---------------- D2: bucket scan (bbase excl, gcur init, row_start sentinel) ----------------
__global__ __launch_bounds__(512) void k_bscan(const int* __restrict__ bcnt,
                                               int* __restrict__ bbase,
                                               int* __restrict__ gcur,
                                               int* __restrict__ row_start,
                                               int nb, int n, int e) {
    __shared__ int sh[512];
    int v = (threadIdx.x < nb) ? bcnt[threadIdx.x] : 0;
    sh[threadIdx.x] = v;
    __syncthreads();
    for (int off = 1; off < 512; off <<= 1) {
        int t = (threadIdx.x >= off) ? sh[threadIdx.x - off] : 0;
        __syncthreads();
        sh[threadIdx.x] += t;
        __syncthreads();
    }
    int excl = sh[threadIdx.x] - v;
    if (threadIdx.x < nb) {
        bbase[threadIdx.x] = excl;
        gcur[threadIdx.x] = excl;
    }
    if (threadIdx.x == 0) {
        bbase[nb] = e;
        row_start[n] = e;  // sentinel for gather
    }
}

// ---------------- D3: fused coarse scatter + MFMA GEMM ----------------
// blocks [0, ebl): scatterA  -> coarse[p] = (src<<8)|(dst&255), bucket-contiguous
// blocks [ebl, ..): gemm     -> hs = bf16(x @ W)   (unscaled)
__global__ __launch_bounds__(256) void k_main(
    const int* __restrict__ src, const int* __restrict__ dst,
    int* __restrict__ gcur, unsigned int* __restrict__ coarse,
    const float* __restrict__ x, const unsigned short* __restrict__ whi,
    unsigned short* __restrict__ hs, int e, int n, int ebl) {
    __shared__ unsigned short Bs[FDIM * FDIM];  // 32 KB (hi plane only)
    __shared__ int cur[NBMAX];                  // 2 KB

    if ((int)blockIdx.x < ebl) {
        // ---- scatterA ----
        for (int i = threadIdx.x; i < NBMAX; i += 256) cur[i] = 0;
        __syncthreads();
        int base = blockIdx.x * EPB;
        int end = min(base + EPB, e);
        for (int i = base + threadIdx.x; i < end; i += 256) atomicAdd(&cur[dst[i] >> 8], 1);
        __syncthreads();
        for (int i = threadIdx.x; i < NBMAX; i += 256) {
            int c = cur[i];
            cur[i] = c ? atomicAdd(&gcur[i], c) : 0;
        }
        __syncthreads();
        for (int i = base + threadIdx.x; i < end; i += 256) {
            int d = dst[i];
            int p = atomicAdd(&cur[d >> 8], 1);
            coarse[p] = ((unsigned)src[i] << 8) | (unsigned)(d & 255);
        }
    } else {
        // ---- gemm ----
        {
            // stage whi with XOR swizzle on 16B granules: g -> g^(n&15)
            const float4* g4 = (const float4*)whi;
            float4* l4 = (float4*)Bs;
            for (int i = threadIdx.x; i < 2048; i += 256) {
                int nn = i >> 4;
                int g = i & 15;
                l4[nn * 16 + (g ^ (nn & 15))] = g4[i];
            }
        }
        __syncthreads();

        const int lane = threadIdx.x & 63;
        const int wid = threadIdx.x >> 6;
        const int m = lane & 15;
        const int quad = lane >> 4;
        const int row0 = ((int)blockIdx.x - ebl) * 64 + wid * 16;

        int rowA = row0 + m;
        if (rowA >= n) rowA = n - 1;
        const float* xr = x + (size_t)rowA * FDIM;

        f32x4 acc[8];
        #pragma unroll
        for (int ct = 0; ct < 8; ++ct) acc[ct] = (f32x4){0.f, 0.f, 0.f, 0.f};

        #pragma unroll
        for (int kc = 0; kc < 4; ++kc) {
            const int kb = kc * 32 + quad * 8;
            float4 xa = *(const float4*)(xr + kb);
            float4 xb = *(const float4*)(xr + kb + 4);
            float v[8] = {xa.x, xa.y, xa.z, xa.w, xb.x, xb.y, xb.z, xb.w};
            bf16x8 ahi, alo;
            #pragma unroll
            for (int j = 0; j < 8; ++j) {
                unsigned short hh = f2bf(v[j]);
                ahi[j] = (short)hh;
                alo[j] = (short)f2bf(v[j] - __uint_as_float(((unsigned)hh) << 16));
            }
            const int g = kc * 4 + quad;
            #pragma unroll
            for (int ct = 0; ct < 8; ++ct) {
                int nidx = ct * 16 + m;
                const bf16x8 bhi = *(const bf16x8*)(Bs + (size_t)nidx * FDIM + (g ^ m) * 8);
                acc[ct] = __builtin_amdgcn_mfma_f32_16x16x32_bf16(ahi, bhi, acc[ct], 0, 0, 0);
                acc[ct] = __builtin_amdgcn_mfma_f32_16x16x32_bf16(alo, bhi, acc[ct], 0, 0, 0);
            }
        }

        // epilogue: D[row=quad*4+r][col=ct*16+m], unscaled
        #pragma unroll
        for (int r = 0; r < 4; ++r) {
            int row = row0 + quad * 4 + r;
            if (row >= n) continue;
            unsigned short* hrow = hs + (size_t)row * FDIM;
            #pragma unroll
            for (int ct = 0; ct < 8; ++ct) hrow[ct * 16 + m] = f2bf(acc[ct][r]);
        }
    }
}

// ---------------- D4: fused per-bucket finalize (dinv, row_start, ebuf) ----------------
__global__ __launch_bounds__(256) void k_bfin(const unsigned int* __restrict__ coarse,
                                              const int* __restrict__ bbase,
                                              float* __restrict__ dinv,
                                              int* __restrict__ row_start,
                                              int* __restrict__ ebuf, int n) {
    __shared__ int ld[256];
    __shared__ int sc[256];
    __shared__ int cur[256];
    int b = blockIdx.x;
    int s = bbase[b], t = bbase[b + 1];
    ld[threadIdx.x] = 0;
    __syncthreads();
    for (int i = s + threadIdx.x; i < t; i += 256) atomicAdd(&ld[coarse[i] & 255u], 1);
    __syncthreads();
    int v = ld[threadIdx.x];  // deg-1 of this node
    sc[threadIdx.x] = v;
    __syncthreads();
    for (int off = 1; off < 256; off <<= 1) {
        int tv = (threadIdx.x >= off) ? sc[threadIdx.x - off] : 0;
        __syncthreads();
        sc[threadIdx.x] += tv;
        __syncthreads();
    }
    int rs = s + sc[threadIdx.x] - v;  // bucket base + exclusive scan
    cur[threadIdx.x] = rs;
    int node = b * 256 + threadIdx.x;
    if (node < n) {
        dinv[node] = rsqrtf((float)(v + 1));
        row_start[node] = rs;
    }
    __syncthreads();
    for (int i = s + threadIdx.x; i < t; i += 256) {
        unsigned int p = coarse[i];
        int pos = atomicAdd(&cur[p & 255u], 1);
        ebuf[pos] = (int)(p >> 8);
    }
}

// ---------------- D5: gather: out[i] = dinv[i]*(dinv[i]*h[i] + sum dinv[s]*h[s]) + b ----------------
__global__ __launch_bounds__(256) void k_gather(
    const unsigned short* __restrict__ hs, const int* __restrict__ ebuf,
    const int* __restrict__ row_start, const float* __restrict__ dinv,
    const float* __restrict__ bias, float* __restrict__ out, int n) {
    int i = blockIdx.x * 4 + (threadIdx.x >> 6);
    if (i >= n) return;
    int lane = threadIdx.x & 63;

    int beg = row_start[i];
    int end = row_start[i + 1];
    float di = dinv[i];

    unsigned int u = ((const unsigned int*)(hs + (size_t)i * FDIM))[lane];
    float ax = di * __uint_as_float(u << 16);
    float ay = di * __uint_as_float(u & 0xffff0000u);

    int j = beg;
    for (; j + 3 < end; j += 4) {
        int s0 = ebuf[j], s1 = ebuf[j + 1], s2 = ebuf[j + 2], s3 = ebuf[j + 3];
        float d0 = dinv[s0], d1 = dinv[s1], d2 = dinv[s2], d3 = dinv[s3];
        unsigned int u0 = ((const unsigned int*)(hs + (size_t)s0 * FDIM))[lane];
        unsigned int u1 = ((const unsigned int*)(hs + (size_t)s1 * FDIM))[lane];
        unsigned int u2 = ((const unsigned int*)(hs + (size_t)s2 * FDIM))[lane];
        unsigned int u3 = ((const unsigned int*)(hs + (size_t)s3 * FDIM))[lane];
        ax = fmaf(d0, __uint_as_float(u0 << 16), ax);
        ay = fmaf(d0, __uint_as_float(u0 & 0xffff0000u), ay);
        ax = fmaf(d1, __uint_as_float(u1 << 16), ax);
        ay = fmaf(d1, __uint_as_float(u1 & 0xffff0000u), ay);
        ax = fmaf(d2, __uint_as_float(u2 << 16), ax);
        ay = fmaf(d2, __uint_as_float(u2 & 0xffff0000u), ay);
        ax = fmaf(d3, __uint_as_float(u3 << 16), ax);
        ay = fmaf(d3, __uint_as_float(u3 & 0xffff0000u), ay);
    }
    for (; j < end; ++j) {
        int s0 = ebuf[j];
        float d0 = dinv[s0];
        unsigned int u0 = ((const unsigned int*)(hs + (size_t)s0 * FDIM))[lane];
        ax = fmaf(d0, __uint_as_float(u0 << 16), ax);
        ay = fmaf(d0, __uint_as_float(u0 & 0xffff0000u), ay);
    }

    float2 bb = ((const float2*)bias)[lane];
    float2 r = make_float2(fmaf(ax, di, bb.x), fmaf(ay, di, bb.y));
    ((float2*)(out + (size_t)i * FDIM))[lane] = r;
}

extern "C" void kernel_launch(void* const* d_in, const int* in_sizes, int n_in,
                              void* d_out, int out_size, void* d_ws, size_t ws_size,
                              hipStream_t stream) {
    const float* x  = (const float*)d_in[0];
    const int*   ei = (const int*)d_in[1];     // [2, E] int32
    const float* W  = (const float*)d_in[2];
    const float* b  = (const float*)d_in[3];

    const int n = in_sizes[0] / FDIM;
    const int e = in_sizes[1] / 2;
    const int* src = ei;
    const int* dst = ei + e;
    float* out = (float*)d_out;

    const int nb = (n + 255) >> 8;              // node buckets
    const int ebl = (e + EPB - 1) / EPB;        // edge blocks
    const int gemmbl = (n + 63) / 64;

    char* ws = (char*)d_ws;
    size_t off = 0;
    auto alloc = [&](size_t bytes) {
        char* p = ws + off;
        off += (bytes + 511) & ~(size_t)511;
        return p;
    };
    float*          dinv      = (float*)alloc((size_t)n * 4);
    int*            row_start = (int*)alloc((size_t)(n + 1) * 4);
    int*            bcnt      = (int*)alloc((size_t)NBMAX * 4);
    int*            bbase     = (int*)alloc((size_t)(NBMAX + 1) * 4);
    int*            gcur      = (int*)alloc((size_t)NBMAX * 4);
    unsigned short* whi       = (unsigned short*)alloc((size_t)FDIM * FDIM * 2);
    unsigned int*   coarse    = (unsigned int*)alloc((size_t)e * 4);
    int*            ebuf      = (int*)alloc((size_t)e * 4);
    unsigned short* hs        = (unsigned short*)alloc((size_t)n * FDIM * 2);

    hipMemsetAsync(bcnt, 0, (size_t)NBMAX * 4, stream);

    k_prep<<<ebl + 64, 256, 0, stream>>>(dst, bcnt, W, whi, e, ebl);
    k_bscan<<<1, 512, 0, stream>>>(bcnt, bbase, gcur, row_start, nb, n, e);
    k_main<<<ebl + gemmbl, 256, 0, stream>>>(src, dst, gcur, coarse, x, whi, hs, e, n, ebl);
    k_bfin<<<nb, 256, 0, stream>>>(coarse, bbase, dinv, row_start, ebuf, n);
    {
        int blocks = (n + 3) / 4;
        k_gather<<<blocks, 256, 0, stream>>>(hs, ebuf, row_start, dinv, b, out, n);
    }
}